// Round 13
// baseline (79.694 us; speedup 1.0000x reference)
//
#include <hip/hip_runtime.h>

// BPS pipeline v13: v11 stage_ang (+float4 x-broadcast reads) and scan+out FUSED
// into one 64-block kernel via decoupled lookback (flags self-init: poison!=1).
// d_out = f32[2L]: [0,L) = real(x*exp(i*ph)), [L,2L) = ph = unwrap(ang)/4.

#define LN   65536
#define PI_F 3.14159265358979323846f
#define TWO_PI_F 6.2831853071795864769f

#define CORR(dd) (((dd) < -PI_F) ? 1 : (((dd) > PI_F) ? -1 : 0))

// Stage 1: per block of 64 outputs. Thread (m = t&63, seg = t>>6) owns rows
// seg*48..seg*48+47 of the 192-row (64-halo) dist tile for column m.
// dist -> P1 (prefix along l) -> box1 = P1 diff -> Q (prefix of box1) -> mvg = Q diff.
__global__ __launch_bounds__(256) void v13_stage_ang(const float* __restrict__ xr,
                                                     const float* __restrict__ xi,
                                                     const float* __restrict__ temp,
                                                     float* __restrict__ ang_out) {
    __shared__ __align__(16) float P1[64 * 193]; // P1[m][li] (pad 193); reused as Q[m*131+j]
    __shared__ __align__(16) float2 xs2[192];    // staged x halo tile (interleaved re,im)
    __shared__ float tot1[4][64];
    __shared__ float tot2[4][64];
    __shared__ float s4v[64], c4v[64];

    const int t   = threadIdx.x;
    const int l0  = blockIdx.x * 64;
    const int m   = t & 63;
    const int seg = t >> 6;          // == wave id; uniform per wave

    if (t < 192) {
        int gl = l0 - 64 + t;
        bool ok = (unsigned)gl < (unsigned)LN;
        xs2[t] = make_float2(ok ? xr[gl] : 0.0f, ok ? xi[gl] : 0.0f);
    }
    if (t < 64) {
        float a4 = (float)t * (PI_F / 32.0f) - PI_F;   // 4*angles[m]
        float s, c; sincosf(a4, &s, &c);
        s4v[t] = s; c4v[t] = c;
    }
    __syncthreads();

    // ---- Phase 1: dist (separable nearest-64QAM quantization) + register prefix ----
    {
        const float am = (float)m * (PI_F / 128.0f) - (PI_F * 0.25f);
        float sm, cm; sincosf(am, &sm, &cm);
        const float SQ = 6.4807406984078602f;   // sqrt(42)
        const float cq = cm * SQ, sq = sm * SQ;
        float pr[48];
        float p = 0.0f;
        #pragma unroll
        for (int i = 0; i < 48; i += 2) {
            int li = seg * 48 + i;
            float4 xx = *(const float4*)(&xs2[li]);   // 2 elements, b128 broadcast
            // element li
            {
                float tr = xx.x * cq - xx.y * sq;
                float ti = xx.x * sq + xx.y * cq;
                float rr = fminf(fmaxf(rintf(fmaf(tr, 0.5f, 3.5f)), 0.0f), 7.0f);
                float ri = fminf(fmaxf(rintf(fmaf(ti, 0.5f, 3.5f)), 0.0f), 7.0f);
                float dr = fmaf(-2.0f, rr, tr + 7.0f);
                float di = fmaf(-2.0f, ri, ti + 7.0f);
                float d = fmaf(dr, dr, di * di) * (1.0f / 42.0f);
                d = ((unsigned)(l0 - 64 + li) < (unsigned)LN) ? d : 0.0f;
                p += d; pr[i] = p;
            }
            // element li+1
            {
                float tr = xx.z * cq - xx.w * sq;
                float ti = xx.z * sq + xx.w * cq;
                float rr = fminf(fmaxf(rintf(fmaf(tr, 0.5f, 3.5f)), 0.0f), 7.0f);
                float ri = fminf(fmaxf(rintf(fmaf(ti, 0.5f, 3.5f)), 0.0f), 7.0f);
                float dr = fmaf(-2.0f, rr, tr + 7.0f);
                float di = fmaf(-2.0f, ri, ti + 7.0f);
                float d = fmaf(dr, dr, di * di) * (1.0f / 42.0f);
                d = ((unsigned)(l0 - 64 + li + 1) < (unsigned)LN) ? d : 0.0f;
                p += d; pr[i + 1] = p;
            }
        }
        tot1[seg][m] = p;
        __syncthreads();
        float off = 0.0f;
        #pragma unroll
        for (int s = 0; s < 3; ++s) if (s < seg) off += tot1[s][m];
        #pragma unroll
        for (int i = 0; i < 48; ++i) P1[m * 193 + seg * 48 + i] = pr[i] + off;
    }
    __syncthreads();

    // ---- Phase 2: box1[j]=P1[63+j]-P1[j-2], j=0..128; register prefix -> Q ----
    const int jn = (seg < 3) ? 33 : 30;
    const int j0 = seg * 33;
    {
        float q[33];
        float p2 = 0.0f;
        #pragma unroll
        for (int i = 0; i < 33; ++i) {
            if (i < jn) {
                int j = j0 + i;
                float hi = P1[m * 193 + 63 + j];
                float lo = (j >= 2) ? P1[m * 193 + j - 2] : 0.0f;
                p2 += hi - lo;
                q[i] = p2;
            }
        }
        tot2[seg][m] = p2;
        __syncthreads();                   // all P1 reads done; reuse as Q
        float off2 = 0.0f;
        #pragma unroll
        for (int s = 0; s < 3; ++s) if (s < seg) off2 += tot2[s][m];
        float* Q = P1;                     // Q[m][j] at m*131 + j
        #pragma unroll
        for (int i = 0; i < 33; ++i) if (i < jn) Q[m * 131 + j0 + i] = q[i] + off2;
    }
    __syncthreads();

    // ---- Phase 3: mvg[r][mm] = Q[mm][r+65]-Q[mm][r]; normalize+softmin+atan2 ----
    {
        const float* Q = P1;
        const float T = temp[0];
        const int lane = t & 63;
        const int sub  = lane & 3;
        const int r    = (t >> 6) * 16 + (lane >> 2);   // 0..63
        const int mb   = sub * 16;

        float v[16];
        float rs = 0.0f, mn = 3.4e38f;
        #pragma unroll
        for (int i = 0; i < 16; ++i) {
            int mm = mb + i;
            float vv = Q[mm * 131 + r + 65] - Q[mm * 131 + r];
            v[i] = vv; rs += vv; mn = fminf(mn, vv);
        }
        rs += __shfl_xor(rs, 1, 64); rs += __shfl_xor(rs, 2, 64);
        mn = fminf(mn, __shfl_xor(mn, 1, 64)); mn = fminf(mn, __shfl_xor(mn, 2, 64));

        float inv = 1.0f / (rs * T);
        float ss = 0.0f, sc = 0.0f;
        #pragma unroll
        for (int i = 0; i < 16; ++i) {
            int mm = mb + i;
            float e = __expf((mn - v[i]) * inv);
            ss = fmaf(e, s4v[mm], ss);
            sc = fmaf(e, c4v[mm], sc);
        }
        ss += __shfl_xor(ss, 1, 64); ss += __shfl_xor(ss, 2, 64);
        sc += __shfl_xor(sc, 1, 64); sc += __shfl_xor(sc, 2, 64);
        if (sub == 0) ang_out[l0 + r] = atan2f(ss, sc);
    }
}

// Fused scan+out: 64 blocks x 256 thr x 4 elem. Local correction scan, publish
// block total (release flag; poison 0xAA != 1 so flags self-initialize), lookback
// over predecessors (all 64 blocks co-resident on 256 CUs -> no deadlock), emit.
__global__ __launch_bounds__(256) void v13_scan_out(const float* __restrict__ xr,
                                                    const float* __restrict__ xi,
                                                    const float* __restrict__ ang,
                                                    int* __restrict__ partial,
                                                    int* __restrict__ flags,
                                                    float* __restrict__ out_base) {
    __shared__ int wtot[4];
    __shared__ int s_boff;
    const int t = threadIdx.x;
    const int b = blockIdx.x;
    const int e = b * 256 + t;
    const int i4 = e * 4;

    float4 a = *(const float4*)(ang + i4);
    float prev = (i4 == 0) ? 0.0f : ang[i4 - 1];

    int s0 = CORR(a.x - prev);
    int s1 = CORR(a.y - a.x);
    int s2 = CORR(a.z - a.y);
    int s3 = CORR(a.w - a.z);
    int k0 = s0, k1 = k0 + s1, k2 = k1 + s2, k3 = k2 + s3;

    const int lane = t & 63, wv = t >> 6;
    int scan = k3;
    #pragma unroll
    for (int off = 1; off < 64; off <<= 1) {
        int v = __shfl_up(scan, off, 64);
        if (lane >= off) scan += v;
    }
    if (lane == 63) wtot[wv] = scan;
    __syncthreads();
    int woff = 0;
    #pragma unroll
    for (int j = 0; j < 3; ++j) if (j < wv) woff += wtot[j];
    const int excl = woff + scan - k3;   // thread-exclusive prefix within block

    // publish block total (wave 0, lane 0) then lookback (wave 0, lanes < b)
    if (t == 0) {
        int btot = wtot[0] + wtot[1] + wtot[2] + wtot[3];
        __hip_atomic_store(&partial[b], btot, __ATOMIC_RELAXED, __HIP_MEMORY_SCOPE_AGENT);
        __hip_atomic_store(&flags[b], 1, __ATOMIC_RELEASE, __HIP_MEMORY_SCOPE_AGENT);
    }
    if (t < 64) {
        int v = 0;
        if (t < b) {
            while (__hip_atomic_load(&flags[t], __ATOMIC_ACQUIRE, __HIP_MEMORY_SCOPE_AGENT) != 1) {}
            v = __hip_atomic_load(&partial[t], __ATOMIC_RELAXED, __HIP_MEMORY_SCOPE_AGENT);
        }
        #pragma unroll
        for (int off = 1; off < 64; off <<= 1) v += __shfl_xor(v, off, 64);
        if (t == 0) s_boff = v;
    }
    __syncthreads();
    const int boff = s_boff;

    float4 xa = *(const float4*)(xr + i4);
    float4 xb = *(const float4*)(xi + i4);
    float ph0 = (a.x + TWO_PI_F * (float)(boff + excl + k0)) * 0.25f;
    float ph1 = (a.y + TWO_PI_F * (float)(boff + excl + k1)) * 0.25f;
    float ph2 = (a.z + TWO_PI_F * (float)(boff + excl + k2)) * 0.25f;
    float ph3 = (a.w + TWO_PI_F * (float)(boff + excl + k3)) * 0.25f;
    float s0f, c0f, s1f, c1f, s2f, c2f, s3f, c3f;
    sincosf(ph0, &s0f, &c0f); sincosf(ph1, &s1f, &c1f);
    sincosf(ph2, &s2f, &c2f); sincosf(ph3, &s3f, &c3f);
    float4 re = make_float4(xa.x * c0f - xb.x * s0f, xa.y * c1f - xb.y * s1f,
                            xa.z * c2f - xb.z * s2f, xa.w * c3f - xb.w * s3f);
    *(float4*)(out_base + i4)      = re;
    *(float4*)(out_base + LN + i4) = make_float4(ph0, ph1, ph2, ph3);
}

extern "C" void kernel_launch(void* const* d_in, const int* in_sizes, int n_in,
                              void* d_out, int out_size, void* d_ws, size_t ws_size,
                              hipStream_t stream) {
    (void)in_sizes; (void)n_in; (void)out_size; (void)ws_size;
    const float* xr   = (const float*)d_in[0];
    const float* xi   = (const float*)d_in[1];
    const float* temp = (const float*)d_in[5];

    float* ang     = (float*)d_ws;                                   // L f32
    int*   partial = (int*)((char*)d_ws + LN * sizeof(float));       // 64 i32
    int*   flags   = (int*)((char*)d_ws + LN * sizeof(float) + 256); // 64 i32

    v13_stage_ang<<<LN / 64, 256, 0, stream>>>(xr, xi, temp, ang);
    v13_scan_out <<<64, 256, 0, stream>>>(xr, xi, ang, partial, flags, (float*)d_out);
}

// Round 14
// 76.714 us; speedup vs baseline: 1.0389x; 1.0389x over previous
//
#include <hip/hip_runtime.h>

// BPS pipeline v14: 128-output tiles (halo redundancy 3x->2x), 512 thr/block,
// scalar LDS x reads; fused lookback scan+out (v13, validated).
// d_out = f32[2L]: [0,L) = real(x*exp(i*ph)), [L,2L) = ph = unwrap(ang)/4.

#define LN   65536
#define PI_F 3.14159265358979323846f
#define TWO_PI_F 6.2831853071795864769f

#define CORR(dd) (((dd) < -PI_F) ? 1 : (((dd) > PI_F) ? -1 : 0))

// Stage 1: block handles 128 outputs; 256-row tile (64-halo each side).
// Thread (m = t&63, seg = t>>6 in 0..7) owns rows seg*32..seg*32+31 for column m.
// dist -> P1 (prefix along l) -> box1 = P1 diff -> Q (prefix of box1) -> mvg = Q diff.
__global__ __launch_bounds__(512) void v14_stage_ang(const float* __restrict__ xr,
                                                     const float* __restrict__ xi,
                                                     const float* __restrict__ temp,
                                                     float* __restrict__ ang_out) {
    __shared__ float P1[64 * 257];       // P1[m][li], li=0..255 (pad 257); reused as Q[m*195+j]
    __shared__ float xsr[256], xsi[256]; // staged x halo tile
    __shared__ float tot1[8][64];
    __shared__ float tot2[8][64];
    __shared__ float s4v[64], c4v[64];

    const int t   = threadIdx.x;
    const int l0  = blockIdx.x * 128;
    const int m   = t & 63;
    const int seg = t >> 6;              // wave id; uniform per wave

    if (t < 256) {
        int gl = l0 - 64 + t;
        bool ok = (unsigned)gl < (unsigned)LN;
        xsr[t] = ok ? xr[gl] : 0.0f;
        xsi[t] = ok ? xi[gl] : 0.0f;
    }
    if (t >= 448) {                      // separate wave fills trig table
        int mm = t - 448;
        float a4 = (float)mm * (PI_F / 32.0f) - PI_F;   // 4*angles[mm]
        float s, c; sincosf(a4, &s, &c);
        s4v[mm] = s; c4v[mm] = c;
    }
    __syncthreads();

    // ---- Phase 1: dist (separable nearest-64QAM quantization) + register prefix ----
    {
        const float am = (float)m * (PI_F / 128.0f) - (PI_F * 0.25f);
        float sm, cm; sincosf(am, &sm, &cm);
        const float SQ = 6.4807406984078602f;   // sqrt(42)
        const float cq = cm * SQ, sq = sm * SQ;
        float pr[32];
        float p = 0.0f;
        #pragma unroll
        for (int i = 0; i < 32; ++i) {
            int li = seg * 32 + i;
            float a = xsr[li], b = xsi[li];     // LDS b32 broadcast
            float tr = a * cq - b * sq;
            float ti = a * sq + b * cq;
            float rr = fminf(fmaxf(rintf(fmaf(tr, 0.5f, 3.5f)), 0.0f), 7.0f);
            float ri = fminf(fmaxf(rintf(fmaf(ti, 0.5f, 3.5f)), 0.0f), 7.0f);
            float dr = fmaf(-2.0f, rr, tr + 7.0f);
            float di = fmaf(-2.0f, ri, ti + 7.0f);
            float d = fmaf(dr, dr, di * di) * (1.0f / 42.0f);
            d = ((unsigned)(l0 - 64 + li) < (unsigned)LN) ? d : 0.0f;  // conv zero-pad
            p += d;
            pr[i] = p;
        }
        tot1[seg][m] = p;
        __syncthreads();
        float off = 0.0f;
        #pragma unroll
        for (int s = 0; s < 7; ++s) if (s < seg) off += tot1[s][m];
        #pragma unroll
        for (int i = 0; i < 32; ++i) P1[m * 257 + seg * 32 + i] = pr[i] + off;
    }
    __syncthreads();

    // ---- Phase 2: box1[j] = P1[63+j] - P1[j-2], j=0..192 (193 vals);
    //      register prefix -> Q[m][j] (reuses P1 after barrier) ----
    const int j0 = seg * 25;
    const int jn = (seg < 7) ? 25 : 18;      // 7*25 + 18 = 193
    {
        float q[25];
        float p2 = 0.0f;
        #pragma unroll
        for (int i = 0; i < 25; ++i) {
            if (i < jn) {
                int j = j0 + i;
                float hi = P1[m * 257 + 63 + j];
                float lo = (j >= 2) ? P1[m * 257 + j - 2] : 0.0f;
                p2 += hi - lo;
                q[i] = p2;
            }
        }
        tot2[seg][m] = p2;
        __syncthreads();                     // all P1 reads done; reuse storage as Q
        float off2 = 0.0f;
        #pragma unroll
        for (int s = 0; s < 7; ++s) if (s < seg) off2 += tot2[s][m];
        float* Q = P1;                       // Q[m][j] at m*195 + j
        #pragma unroll
        for (int i = 0; i < 25; ++i) if (i < jn) Q[m * 195 + j0 + i] = q[i] + off2;
    }
    __syncthreads();

    // ---- Phase 3: mvg[r][mm] = Q[mm][r+65]-Q[mm][r], r=0..127; 4 lanes/row ----
    {
        const float* Q = P1;
        const float T = temp[0];
        const int sub = t & 3;               // 4 lanes share one output row
        const int r   = t >> 2;              // 0..127
        const int mb  = sub * 16;

        float v[16];
        float rs = 0.0f, mn = 3.4e38f;
        #pragma unroll
        for (int i = 0; i < 16; ++i) {
            int mm = mb + i;
            float vv = Q[mm * 195 + r + 65] - Q[mm * 195 + r];
            v[i] = vv; rs += vv; mn = fminf(mn, vv);
        }
        rs += __shfl_xor(rs, 1, 64); rs += __shfl_xor(rs, 2, 64);
        mn = fminf(mn, __shfl_xor(mn, 1, 64)); mn = fminf(mn, __shfl_xor(mn, 2, 64));

        // softmax(-mvg_norm/T) weights exp((mn-v)/(rs*T)); denominator cancels in atan2
        float inv = 1.0f / (rs * T);
        float ss = 0.0f, sc = 0.0f;
        #pragma unroll
        for (int i = 0; i < 16; ++i) {
            int mm = mb + i;
            float e = __expf((mn - v[i]) * inv);
            ss = fmaf(e, s4v[mm], ss);
            sc = fmaf(e, c4v[mm], sc);
        }
        ss += __shfl_xor(ss, 1, 64); ss += __shfl_xor(ss, 2, 64);
        sc += __shfl_xor(sc, 1, 64); sc += __shfl_xor(sc, 2, 64);
        if (sub == 0) ang_out[l0 + r] = atan2f(ss, sc);
    }
}

// Fused scan+out (v13, validated): 64 blocks x 256 thr x 4 elem. Local correction
// scan, publish block total (release flag; poison 0xAA != 1 -> flags self-init),
// lookback over predecessors (64 blocks co-resident), emit outputs.
__global__ __launch_bounds__(256) void v14_scan_out(const float* __restrict__ xr,
                                                    const float* __restrict__ xi,
                                                    const float* __restrict__ ang,
                                                    int* __restrict__ partial,
                                                    int* __restrict__ flags,
                                                    float* __restrict__ out_base) {
    __shared__ int wtot[4];
    __shared__ int s_boff;
    const int t = threadIdx.x;
    const int b = blockIdx.x;
    const int e = b * 256 + t;
    const int i4 = e * 4;

    float4 a = *(const float4*)(ang + i4);
    float prev = (i4 == 0) ? 0.0f : ang[i4 - 1];

    int s0 = CORR(a.x - prev);
    int s1 = CORR(a.y - a.x);
    int s2 = CORR(a.z - a.y);
    int s3 = CORR(a.w - a.z);
    int k0 = s0, k1 = k0 + s1, k2 = k1 + s2, k3 = k2 + s3;

    const int lane = t & 63, wv = t >> 6;
    int scan = k3;
    #pragma unroll
    for (int off = 1; off < 64; off <<= 1) {
        int v = __shfl_up(scan, off, 64);
        if (lane >= off) scan += v;
    }
    if (lane == 63) wtot[wv] = scan;
    __syncthreads();
    int woff = 0;
    #pragma unroll
    for (int j = 0; j < 3; ++j) if (j < wv) woff += wtot[j];
    const int excl = woff + scan - k3;   // thread-exclusive prefix within block

    if (t == 0) {
        int btot = wtot[0] + wtot[1] + wtot[2] + wtot[3];
        __hip_atomic_store(&partial[b], btot, __ATOMIC_RELAXED, __HIP_MEMORY_SCOPE_AGENT);
        __hip_atomic_store(&flags[b], 1, __ATOMIC_RELEASE, __HIP_MEMORY_SCOPE_AGENT);
    }
    if (t < 64) {
        int v = 0;
        if (t < b) {
            while (__hip_atomic_load(&flags[t], __ATOMIC_ACQUIRE, __HIP_MEMORY_SCOPE_AGENT) != 1) {}
            v = __hip_atomic_load(&partial[t], __ATOMIC_RELAXED, __HIP_MEMORY_SCOPE_AGENT);
        }
        #pragma unroll
        for (int off = 1; off < 64; off <<= 1) v += __shfl_xor(v, off, 64);
        if (t == 0) s_boff = v;
    }
    __syncthreads();
    const int boff = s_boff;

    float4 xa = *(const float4*)(xr + i4);
    float4 xb = *(const float4*)(xi + i4);
    float ph0 = (a.x + TWO_PI_F * (float)(boff + excl + k0)) * 0.25f;
    float ph1 = (a.y + TWO_PI_F * (float)(boff + excl + k1)) * 0.25f;
    float ph2 = (a.z + TWO_PI_F * (float)(boff + excl + k2)) * 0.25f;
    float ph3 = (a.w + TWO_PI_F * (float)(boff + excl + k3)) * 0.25f;
    float s0f, c0f, s1f, c1f, s2f, c2f, s3f, c3f;
    sincosf(ph0, &s0f, &c0f); sincosf(ph1, &s1f, &c1f);
    sincosf(ph2, &s2f, &c2f); sincosf(ph3, &s3f, &c3f);
    float4 re = make_float4(xa.x * c0f - xb.x * s0f, xa.y * c1f - xb.y * s1f,
                            xa.z * c2f - xb.z * s2f, xa.w * c3f - xb.w * s3f);
    *(float4*)(out_base + i4)      = re;
    *(float4*)(out_base + LN + i4) = make_float4(ph0, ph1, ph2, ph3);
}

extern "C" void kernel_launch(void* const* d_in, const int* in_sizes, int n_in,
                              void* d_out, int out_size, void* d_ws, size_t ws_size,
                              hipStream_t stream) {
    (void)in_sizes; (void)n_in; (void)out_size; (void)ws_size;
    const float* xr   = (const float*)d_in[0];
    const float* xi   = (const float*)d_in[1];
    const float* temp = (const float*)d_in[5];

    float* ang     = (float*)d_ws;                                   // L f32
    int*   partial = (int*)((char*)d_ws + LN * sizeof(float));       // 64 i32
    int*   flags   = (int*)((char*)d_ws + LN * sizeof(float) + 256); // 64 i32

    v14_stage_ang<<<LN / 128, 512, 0, stream>>>(xr, xi, temp, ang);
    v14_scan_out <<<64, 256, 0, stream>>>(xr, xi, ang, partial, flags, (float*)d_out);
}